// Round 4
// baseline (91.889 us; speedup 1.0000x reference)
//
#include <hip/hip_runtime.h>
#include <math.h>

#define NN 8192
#define DD 128
#define BM 128        // rows per block (4 waves x 32)
#define BN 64         // cols per j-tile
#define NPART 16      // grid = 64*16 = 1024 blocks
#define JRANGE (NN / NPART)   // 512
#define NTILES (JRANGE / BN)  // 8

typedef __attribute__((ext_vector_type(4))) int i32x4;

// ws byte offsets
#define WS_SQ   0                         // 8192 floats
#define WS_CI   32768                     // 8192 floats (per-row combined scale)
#define WS_PT   65536                     // 32 floats
#define WS_PC   65792                     // 32 floats
#define WS_HPG  69632                     // 16*8192 floats
#define WS_HNG  (69632 + 524288)
#define WS_AH   (69632 + 2 * 524288)      // 1 MB
#define WS_AL   (69632 + 2 * 524288 + 1048576)

// fused: per-row sqnorm + per-row absmax + i8 hi/lo quantize
// one row per 32-lane half-wave; block = 256 thr = 8 rows
__global__ __launch_bounds__(256)
void prepq_k(const float* __restrict__ emb, float* __restrict__ sq,
             float* __restrict__ ci, int* __restrict__ aH, int* __restrict__ aL) {
    const int lane = threadIdx.x & 63;
    const int w    = threadIdx.x >> 6;
    const int half = lane >> 5;           // 0/1: which row in this wave
    const int l32  = lane & 31;
    const int row  = blockIdx.x * 8 + w * 2 + half;

    float4 v = reinterpret_cast<const float4*>(emb)[row * 32 + l32];
    float s = 0.f, m = 0.f;
    s = fmaf(v.x, v.x, s); m = fmaxf(m, fabsf(v.x));
    s = fmaf(v.y, v.y, s); m = fmaxf(m, fabsf(v.y));
    s = fmaf(v.z, v.z, s); m = fmaxf(m, fabsf(v.z));
    s = fmaf(v.w, v.w, s); m = fmaxf(m, fabsf(v.w));
#pragma unroll
    for (int off = 1; off < 32; off <<= 1) {   // stays within 32-lane half
        s += __shfl_xor(s, off, 64);
        m = fmaxf(m, __shfl_xor(m, off, 64));
    }
    m = fmaxf(m, 1e-30f);
    float sA  = m * (1.0f / 127.0f);
    float inv = 127.0f / m;
    int h = 0, l = 0;
#define QSTEP(X, K) { \
        float a = rintf((X) * inv); \
        a = fminf(fmaxf(a, -127.f), 127.f); \
        float r = fmaf(-a, sA, (X)); \
        float b = rintf(r * inv * 256.0f); \
        b = fminf(fmaxf(b, -127.f), 127.f); \
        h |= ((int)a & 255) << (8 * (K)); \
        l |= ((int)b & 255) << (8 * (K)); }
    QSTEP(v.x, 0) QSTEP(v.y, 1) QSTEP(v.z, 2) QSTEP(v.w, 3)
#undef QSTEP
    aH[row * 32 + l32] = h;
    aL[row * 32 + l32] = l;
    if (l32 == 0) {
        sq[row] = s;
        ci[row] = sA * 0.08838834764831845f;   // sqrt(2)/16 -> ci*cj = 2*sAi*sAj/256
    }
}

__global__ __launch_bounds__(256, 4)
void hardest_k(const int* __restrict__ aH, const int* __restrict__ aL,
               const int* __restrict__ lab, const float* __restrict__ sq,
               const float* __restrict__ ci,
               float* __restrict__ hpg_o, float* __restrict__ hng_o) {
    const int tid  = threadIdx.x;
    const int w    = tid >> 6;
    const int lane = tid & 63;
    const int lrow = lane & 15;
    const int lk   = lane >> 4;
    const int ib   = (int)blockIdx.x >> 4;
    const int part = (int)blockIdx.x & 15;
    const int i0   = ib * BM;
    const int jbeg = part * JRANGE;

    // persistent A fragments: 2 strips of 16 rows, K=128 in 2 chunks, hi+lo
    i32x4 ah[2][2], al[2][2];
#pragma unroll
    for (int s = 0; s < 2; ++s) {
        int row = i0 + w * 32 + s * 16 + lrow;
#pragma unroll
        for (int q = 0; q < 2; ++q) {
            ah[s][q] = *reinterpret_cast<const i32x4*>(&aH[row * 32 + q * 16 + lk * 4]);
            al[s][q] = *reinterpret_cast<const i32x4*>(&aL[row * 32 + q * 16 + lk * 4]);
        }
    }
    int   li[2][4];
    float cih[2][4], hpg[2][4], hng[2][4];
#pragma unroll
    for (int s = 0; s < 2; ++s)
#pragma unroll
        for (int t = 0; t < 4; ++t) {
            int i = i0 + w * 32 + s * 16 + lk * 4 + t;
            li[s][t]  = lab[i];
            cih[s][t] = ci[i];
            hpg[s][t] = -INFINITY;
            hng[s][t] =  INFINITY;
        }

#pragma unroll 1
    for (int jt = 0; jt < NTILES; ++jt) {
        const int j0 = jbeg + jt * BN;
#pragma unroll
        for (int c = 0; c < 4; ++c) {
            const int jrow = j0 + c * 16 + lrow;
            i32x4 bh0 = *reinterpret_cast<const i32x4*>(&aH[jrow * 32 + 0  + lk * 4]);
            i32x4 bh1 = *reinterpret_cast<const i32x4*>(&aH[jrow * 32 + 16 + lk * 4]);
            i32x4 bl0 = *reinterpret_cast<const i32x4*>(&aL[jrow * 32 + 0  + lk * 4]);
            i32x4 bl1 = *reinterpret_cast<const i32x4*>(&aL[jrow * 32 + 16 + lk * 4]);
            i32x4 accA[2], accB[2];
            i32x4 zero = {0, 0, 0, 0};
#pragma unroll
            for (int s = 0; s < 2; ++s) { accA[s] = zero; accB[s] = zero; }
#pragma unroll
            for (int s = 0; s < 2; ++s) {
                accA[s] = __builtin_amdgcn_mfma_i32_16x16x64_i8(ah[s][0], bh0, accA[s], 0, 0, 0);
                accA[s] = __builtin_amdgcn_mfma_i32_16x16x64_i8(ah[s][1], bh1, accA[s], 0, 0, 0);
                accB[s] = __builtin_amdgcn_mfma_i32_16x16x64_i8(ah[s][0], bl0, accB[s], 0, 0, 0);
                accB[s] = __builtin_amdgcn_mfma_i32_16x16x64_i8(ah[s][1], bl1, accB[s], 0, 0, 0);
                accB[s] = __builtin_amdgcn_mfma_i32_16x16x64_i8(al[s][0], bh0, accB[s], 0, 0, 0);
                accB[s] = __builtin_amdgcn_mfma_i32_16x16x64_i8(al[s][1], bh1, accB[s], 0, 0, 0);
            }
            const float sqj = sq[jrow];
            const float cjv = ci[jrow];
            const int   lj  = lab[jrow];
#pragma unroll
            for (int s = 0; s < 2; ++s)
#pragma unroll
                for (int t = 0; t < 4; ++t) {
                    int   e  = (accA[s][t] << 8) + accB[s][t];    // exact, < 2^30
                    float ef = (float)e;
                    float mm = cih[s][t] * cjv;                   // 2*sAi*sAj/256
                    float gg = fmaf(mm, -ef, sqj);                // g = sqj - 2*dot
                    bool same = (li[s][t] == lj);
                    hpg[s][t] = fmaxf(hpg[s][t], same ? gg : -INFINITY);
                    hng[s][t] = fminf(hng[s][t], same ? INFINITY : gg);
                }
        }
    }
    // reduce over the 16 column-lanes sharing each output row
#pragma unroll
    for (int off = 1; off < 16; off <<= 1)
#pragma unroll
        for (int s = 0; s < 2; ++s)
#pragma unroll
            for (int t = 0; t < 4; ++t) {
                hpg[s][t] = fmaxf(hpg[s][t], __shfl_xor(hpg[s][t], off, 64));
                hng[s][t] = fminf(hng[s][t], __shfl_xor(hng[s][t], off, 64));
            }
    if (lrow == 0) {
#pragma unroll
        for (int s = 0; s < 2; ++s)
#pragma unroll
            for (int t = 0; t < 4; ++t) {
                int i = i0 + w * 32 + s * 16 + lk * 4 + t;
                hpg_o[part * NN + i] = hpg[s][t];
                hng_o[part * NN + i] = hng[s][t];
            }
    }
}

__global__ __launch_bounds__(256)
void combine_k(const float* __restrict__ hpg, const float* __restrict__ hng,
               const float* __restrict__ sq, float* __restrict__ pT,
               float* __restrict__ pC) {
    int i = blockIdx.x * 256 + threadIdx.x;
    float hp = -INFINITY, hn = INFINITY;
#pragma unroll
    for (int p = 0; p < NPART; ++p) {
        hp = fmaxf(hp, hpg[p * NN + i]);
        hn = fminf(hn, hng[p * NN + i]);
    }
    float s = sq[i];
    float hp2 = s + hp, hn2 = s + hn;                 // d^2 = sq_i + g
    float hpd = (hp2 == -INFINITY) ? -INFINITY : sqrtf(fmaxf(hp2, 0.f));
    float hnd = (hn2 ==  INFINITY) ?  INFINITY : sqrtf(fmaxf(hn2, 0.f));
    float tl = hpd - hnd + 1.0f;                      // -inf propagates, no NaN
    float tsum = (tl > 0.f) ? tl : 0.f;
    float tcnt = (tl > 0.f) ? 1.f : 0.f;
#pragma unroll
    for (int off = 1; off < 64; off <<= 1) {
        tsum += __shfl_xor(tsum, off, 64);
        tcnt += __shfl_xor(tcnt, off, 64);
    }
    __shared__ float sT[4], sC[4];
    if ((threadIdx.x & 63) == 0) { sT[threadIdx.x >> 6] = tsum; sC[threadIdx.x >> 6] = tcnt; }
    __syncthreads();
    if (threadIdx.x == 0) {
        pT[blockIdx.x] = sT[0] + sT[1] + sT[2] + sT[3];
        pC[blockIdx.x] = sC[0] + sC[1] + sC[2] + sC[3];
    }
}

__global__ __launch_bounds__(64)
void final_k(const float* __restrict__ pT, const float* __restrict__ pC,
             float* __restrict__ out) {
    float t = (threadIdx.x < 32) ? pT[threadIdx.x] : 0.f;
    float c = (threadIdx.x < 32) ? pC[threadIdx.x] : 0.f;
#pragma unroll
    for (int off = 1; off < 32; off <<= 1) {
        t += __shfl_xor(t, off, 64);
        c += __shfl_xor(c, off, 64);
    }
    if (threadIdx.x == 0) out[0] = (c > 0.f) ? t / c : 0.f;
}

extern "C" void kernel_launch(void* const* d_in, const int* in_sizes, int n_in,
                              void* d_out, int out_size, void* d_ws, size_t ws_size,
                              hipStream_t stream) {
    const float* emb = (const float*)d_in[0];
    const int*   lab = (const int*)d_in[1];
    char* ws = (char*)d_ws;
    float* sq  = (float*)(ws + WS_SQ);
    float* ci  = (float*)(ws + WS_CI);
    float* pT  = (float*)(ws + WS_PT);
    float* pC  = (float*)(ws + WS_PC);
    float* hpg = (float*)(ws + WS_HPG);
    float* hng = (float*)(ws + WS_HNG);
    int*   aH  = (int*)(ws + WS_AH);
    int*   aL  = (int*)(ws + WS_AL);

    prepq_k<<<dim3(NN / 8), dim3(256), 0, stream>>>(emb, sq, ci, aH, aL);
    hardest_k<<<dim3((NN / BM) * NPART), dim3(256), 0, stream>>>(aH, aL, lab, sq, ci, hpg, hng);
    combine_k<<<dim3(NN / 256), dim3(256), 0, stream>>>(hpg, hng, sq, pT, pC);
    final_k<<<dim3(1), dim3(64), 0, stream>>>(pT, pC, (float*)d_out);
}